// Round 22
// baseline (113.855 us; speedup 1.0000x reference)
//
#include <hip/hip_runtime.h>
#include <hip/hip_bf16.h>

// GRU cell v22: v16 base (32x32x16 MFMA, wave tile 64x64, 4 waves/256 thr,
// 64-row tiles, 64 KB LDS, 2 blocks/CU, (256,2), fenced rings) with the
// h-pass x-half FUSED into pass 1 (chunks 0-15 compute z AND xh; 8 MFMA/chunk).
// Chunk count 96 -> 80. z parks in d_out (v14/v15-proven thread-private dwords)
// to keep the r-pass register peak ~204 <= 256. acch carries across barriers.
// rh parks in h_l; h-pass is a 16-chunk rh-only sweep. 3 barriers total.

typedef __attribute__((ext_vector_type(8)))  short s8v;            // 8 bf16 = 4 VGPR
typedef __attribute__((ext_vector_type(8)))  unsigned short us8;
typedef __attribute__((ext_vector_type(16))) float f16v;           // 32x32 acc tile
typedef __attribute__((ext_vector_type(4)))  float f4v;

__device__ __forceinline__ float bf2f(unsigned short u) {
  union { unsigned int i; float f; } c; c.i = ((unsigned int)u) << 16; return c.f;
}
__device__ __forceinline__ unsigned short f2bf(float f) {
  __hip_bfloat16 b = __float2bfloat16(f);            // RNE, pairs into v_cvt_pk_bf16_f32
  union { __hip_bfloat16 b; unsigned short u; } c; c.b = b; return c.u;
}
__device__ __forceinline__ unsigned int pk2(float lo, float hi) {
  return (unsigned int)f2bf(lo) | ((unsigned int)f2bf(hi) << 16);
}
__device__ __forceinline__ float sig_(float s)  { return 1.0f / (1.0f + __expf(-s)); }
__device__ __forceinline__ float tanh_(float s) { return 2.0f / (1.0f + __expf(-2.0f * s)) - 1.0f; }

// ---------------- weight prep: fp32 [K][N] -> bf16 32-col fragment tiles ----------------
// Tile (nt, kt) = 32 n x 16 k = 512 shorts (1 KB), lane-major:
//   n = nt*32 + (lane&31), k = kt*16 + (lane>>5)*8 + e ; tile index t = nt*32 + kt.
// wzr: nt 0..7 = Wz/Uz, nt 8..15 = Wr/Ur. whh: nt 0..7 = Wh/Uh. k<256 -> W, else U.
__global__ void gru_prep(const float* __restrict__ Wz, const float* __restrict__ Uz,
                         const float* __restrict__ Wr, const float* __restrict__ Ur,
                         const float* __restrict__ Wh, const float* __restrict__ Uh,
                         unsigned short* __restrict__ wzr, unsigned short* __restrict__ whh) {
  int idx = blockIdx.x * 256 + threadIdx.x;
  if (idx < 512 * 512) {
    int t = idx >> 9, s = idx & 511, lane = s >> 3, e = s & 7;
    int nt = t >> 5, kt = t & 31;
    int n = nt * 32 + (lane & 31);
    int k = kt * 16 + ((lane >> 5) << 3) + e;
    int nn = n & 255;
    float v;
    if (n < 256) v = (k < 256) ? Wz[k * 256 + nn] : Uz[(k - 256) * 256 + nn];
    else         v = (k < 256) ? Wr[k * 256 + nn] : Ur[(k - 256) * 256 + nn];
    wzr[idx] = f2bf(v);
  } else if (idx < 512 * 512 + 256 * 512) {
    int j = idx - 512 * 512;
    int t = j >> 9, s = j & 511, lane = s >> 3, e = s & 7;
    int nt = t >> 5, kt = t & 31;
    int n = nt * 32 + (lane & 31);
    int k = kt * 16 + ((lane >> 5) << 3) + e;
    float v = (k < 256) ? Wh[k * 256 + n] : Uh[(k - 256) * 256 + n];
    whh[j] = f2bf(v);
  }
}

#define MFMA32(a, b, c) __builtin_amdgcn_mfma_f32_32x32x16_bf16((a), (b), (c), 0, 0, 0)

// ---- FUSED pass-1 sweep: 32 chunks; accz over all, acch over chunks 0..15 (x half) ----
// bz/bh rings-3 distance-2; A ring-3 distance-2. Static indices; fenced.
__device__ __forceinline__ void sweep32zh(f16v accz[2][2], f16v acch[2][2],
    const unsigned short* __restrict__ z0p, const unsigned short* __restrict__ z1p,
    const unsigned short* __restrict__ h0p, const unsigned short* __restrict__ h1p,
    const unsigned short* Ax, const unsigned short* Ah, int l31, int hi)
{
  const int r7 = l31 & 7;
  const unsigned short* Ax0 = Ax + l31 * 256;
  const unsigned short* Ax1 = Ax + (32 + l31) * 256;
  const unsigned short* Ah0 = Ah + l31 * 256;
  const unsigned short* Ah1 = Ah + (32 + l31) * 256;
  s8v bz[3][2], bh[3][2], a[3][2];
#pragma unroll
  for (int i = 0; i < 2; ++i) {
    bz[i][0] = *(const s8v*)(z0p + i * 512);
    bz[i][1] = *(const s8v*)(z1p + i * 512);
    bh[i][0] = *(const s8v*)(h0p + i * 512);
    bh[i][1] = *(const s8v*)(h1p + i * 512);
    const int gp = ((i * 2 + hi) ^ r7) * 8;
    a[i][0] = *(const s8v*)(Ax0 + gp);
    a[i][1] = *(const s8v*)(Ax1 + gp);
  }
#pragma unroll
  for (int c = 0; c < 32; ++c) {
    if (c + 2 < 32) {
      const int cn = c + 2;
      const int s = cn % 3;
      bz[s][0] = *(const s8v*)(z0p + cn * 512);
      bz[s][1] = *(const s8v*)(z1p + cn * 512);
      if (cn < 16) {
        bh[s][0] = *(const s8v*)(h0p + cn * 512);
        bh[s][1] = *(const s8v*)(h1p + cn * 512);
      }
      const int kk = cn & 15;
      const int gp = ((kk * 2 + hi) ^ r7) * 8;
      if (cn < 16) { a[s][0] = *(const s8v*)(Ax0 + gp); a[s][1] = *(const s8v*)(Ax1 + gp); }
      else         { a[s][0] = *(const s8v*)(Ah0 + gp); a[s][1] = *(const s8v*)(Ah1 + gp); }
    }
    __builtin_amdgcn_sched_barrier(0);
    const int s = c % 3;
    accz[0][0] = MFMA32(a[s][0], bz[s][0], accz[0][0]);
    accz[0][1] = MFMA32(a[s][0], bz[s][1], accz[0][1]);
    accz[1][0] = MFMA32(a[s][1], bz[s][0], accz[1][0]);
    accz[1][1] = MFMA32(a[s][1], bz[s][1], accz[1][1]);
    if (c < 16) {
      acch[0][0] = MFMA32(a[s][0], bh[s][0], acch[0][0]);
      acch[0][1] = MFMA32(a[s][0], bh[s][1], acch[0][1]);
      acch[1][0] = MFMA32(a[s][1], bh[s][0], acch[1][0]);
      acch[1][1] = MFMA32(a[s][1], bh[s][1], acch[1][1]);
    }
    __builtin_amdgcn_sched_barrier(0);
  }
}

// ---- r-pass sweep: 32 chunks, single gate; B ring-4 distance-3, A ring-3 d-2 ----
__device__ __forceinline__ void sweep32(f16v acc[2][2],
    const unsigned short* __restrict__ b0p, const unsigned short* __restrict__ b1p,
    const unsigned short* Ax, const unsigned short* Ah, int l31, int hi)
{
  const int r7 = l31 & 7;
  const unsigned short* Ax0 = Ax + l31 * 256;
  const unsigned short* Ax1 = Ax + (32 + l31) * 256;
  const unsigned short* Ah0 = Ah + l31 * 256;
  const unsigned short* Ah1 = Ah + (32 + l31) * 256;
  s8v b[4][2];
  s8v a[3][2];
#pragma unroll
  for (int i = 0; i < 3; ++i) {
    b[i][0] = *(const s8v*)(b0p + i * 512);
    b[i][1] = *(const s8v*)(b1p + i * 512);
  }
#pragma unroll
  for (int i = 0; i < 2; ++i) {
    const int gp = ((i * 2 + hi) ^ r7) * 8;
    a[i][0] = *(const s8v*)(Ax0 + gp);
    a[i][1] = *(const s8v*)(Ax1 + gp);
  }
#pragma unroll
  for (int c = 0; c < 32; ++c) {
    if (c + 3 < 32) {
      const int s = (c + 3) & 3;
      b[s][0] = *(const s8v*)(b0p + (c + 3) * 512);
      b[s][1] = *(const s8v*)(b1p + (c + 3) * 512);
    }
    if (c + 2 < 32) {
      const int cn = c + 2;
      const int kk = cn & 15;
      const int gp = ((kk * 2 + hi) ^ r7) * 8;
      const int s = cn % 3;
      if (cn < 16) { a[s][0] = *(const s8v*)(Ax0 + gp); a[s][1] = *(const s8v*)(Ax1 + gp); }
      else         { a[s][0] = *(const s8v*)(Ah0 + gp); a[s][1] = *(const s8v*)(Ah1 + gp); }
    }
    __builtin_amdgcn_sched_barrier(0);
    const int sb = c & 3, sa = c % 3;
    acc[0][0] = MFMA32(a[sa][0], b[sb][0], acc[0][0]);
    acc[0][1] = MFMA32(a[sa][0], b[sb][1], acc[0][1]);
    acc[1][0] = MFMA32(a[sa][1], b[sb][0], acc[1][0]);
    acc[1][1] = MFMA32(a[sa][1], b[sb][1], acc[1][1]);
    __builtin_amdgcn_sched_barrier(0);
  }
}

// ---- h-pass rh-half sweep: 16 chunks, A = h_l (rh); B ring-3 d-2, A ring-3 d-2 ----
__device__ __forceinline__ void sweep16h(f16v acc[2][2],
    const unsigned short* __restrict__ b0p, const unsigned short* __restrict__ b1p,
    const unsigned short* Ah, int l31, int hi)
{
  const int r7 = l31 & 7;
  const unsigned short* Ah0 = Ah + l31 * 256;
  const unsigned short* Ah1 = Ah + (32 + l31) * 256;
  s8v b[3][2], a[3][2];
#pragma unroll
  for (int i = 0; i < 2; ++i) {
    b[i][0] = *(const s8v*)(b0p + i * 512);
    b[i][1] = *(const s8v*)(b1p + i * 512);
    const int gp = ((i * 2 + hi) ^ r7) * 8;
    a[i][0] = *(const s8v*)(Ah0 + gp);
    a[i][1] = *(const s8v*)(Ah1 + gp);
  }
#pragma unroll
  for (int c = 0; c < 16; ++c) {
    if (c + 2 < 16) {
      const int cn = c + 2;
      const int s = cn % 3;
      b[s][0] = *(const s8v*)(b0p + cn * 512);
      b[s][1] = *(const s8v*)(b1p + cn * 512);
      const int gp = ((cn * 2 + hi) ^ r7) * 8;
      a[s][0] = *(const s8v*)(Ah0 + gp);
      a[s][1] = *(const s8v*)(Ah1 + gp);
    }
    __builtin_amdgcn_sched_barrier(0);
    const int s = c % 3;
    acc[0][0] = MFMA32(a[s][0], b[s][0], acc[0][0]);
    acc[0][1] = MFMA32(a[s][0], b[s][1], acc[0][1]);
    acc[1][0] = MFMA32(a[s][1], b[s][0], acc[1][0]);
    acc[1][1] = MFMA32(a[s][1], b[s][1], acc[1][1]);
    __builtin_amdgcn_sched_barrier(0);
  }
}

// swizzled scalar LDS accessors (granule-XOR layout)
__device__ __forceinline__ float ldsA_get(const unsigned short* A, int row, int col) {
  int gp = ((col >> 3) ^ (row & 7));
  return bf2f(A[row * 256 + gp * 8 + (col & 7)]);
}
__device__ __forceinline__ void ldsA_put(unsigned short* A, int row, int col, unsigned short v) {
  int gp = ((col >> 3) ^ (row & 7));
  A[row * 256 + gp * 8 + (col & 7)] = v;
}

// C-tile row for reg q (m74/m101 verified): (q&3) + 8*(q>>2) + 4*hi
#define CROW(q, hi) (((q) & 3) + 8 * ((q) >> 2) + 4 * (hi))

// ---------------- main fused kernel: 64 rows per block, 4 waves ----------------
__global__ __launch_bounds__(256, 2) void gru_main(
    const float* __restrict__ x, const float* __restrict__ hp,
    const unsigned short* __restrict__ wzr, const unsigned short* __restrict__ whh,
    const float* __restrict__ bz, const float* __restrict__ br, const float* __restrict__ bh,
    float* __restrict__ out)
{
  __shared__ __align__(16) unsigned short x_l[64 * 256];   // 32 KB; x (bf16, XOR layout)
  __shared__ __align__(16) unsigned short h_l[64 * 256];   // 32 KB; h_prev, later rh

  const int tid = threadIdx.x;
  const int lane = tid & 63;
  const int wv = tid >> 6;                   // 0..3 : wave's 64-col slice
  const int l31 = lane & 31, hi = lane >> 5;
  const int row0 = blockIdx.x * 64;

  // B tile streams (nt stride 16384 shorts = 32 chunks x 512); wave owns nt wv*2, wv*2+1
  const unsigned short* Bz = wzr + (size_t)(wv * 2) * 16384 + lane * 8;
  const unsigned short* Br = wzr + 131072 + (size_t)(wv * 2) * 16384 + lane * 8;
  const unsigned short* Bh = whh + (size_t)(wv * 2) * 16384 + lane * 8;

  unsigned int* outw = (unsigned int*)out;

  // ---- stage x, h tiles to LDS (fp32 -> bf16), granule-XOR layout; 64 elems/thread/array
  {
    const int srow = tid >> 2;               // 0..63
    const int part = tid & 3;                // 64 cols = 8 granules each
    const float* xs = x  + (size_t)(row0 + srow) * 256 + part * 64;
    const float* hs = hp + (size_t)(row0 + srow) * 256 + part * 64;
    unsigned short* xd = x_l + srow * 256;
    unsigned short* hd = h_l + srow * 256;
    const int r7 = srow & 7;
#pragma unroll
    for (int j = 0; j < 8; ++j) {
      int gp = (part * 8 + j) ^ r7;
      f4v v0 = *(const f4v*)(xs + j * 8);
      f4v v1 = *(const f4v*)(xs + j * 8 + 4);
      us8 o;
      o[0]=f2bf(v0[0]); o[1]=f2bf(v0[1]); o[2]=f2bf(v0[2]); o[3]=f2bf(v0[3]);
      o[4]=f2bf(v1[0]); o[5]=f2bf(v1[1]); o[6]=f2bf(v1[2]); o[7]=f2bf(v1[3]);
      *(us8*)(xd + gp * 8) = o;
    }
#pragma unroll
    for (int j = 0; j < 8; ++j) {
      int gp = (part * 8 + j) ^ r7;
      f4v v0 = *(const f4v*)(hs + j * 8);
      f4v v1 = *(const f4v*)(hs + j * 8 + 4);
      us8 o;
      o[0]=f2bf(v0[0]); o[1]=f2bf(v0[1]); o[2]=f2bf(v0[2]); o[3]=f2bf(v0[3]);
      o[4]=f2bf(v1[0]); o[5]=f2bf(v1[1]); o[6]=f2bf(v1[2]); o[7]=f2bf(v1[3]);
      *(us8*)(hd + gp * 8) = o;
    }
  }
  __syncthreads();                           // B1

  f16v accg[2][2];                           // gate accumulator (z then r)
  f16v acch[2][2];                           // h_hat accumulator (lives across passes)

  // ===== PASS 1 (fused): accg = z pre-act ; acch = x*Wh
  accg[0][0] = (f16v)(0.f); accg[0][1] = (f16v)(0.f);
  accg[1][0] = (f16v)(0.f); accg[1][1] = (f16v)(0.f);
  acch[0][0] = (f16v)(0.f); acch[0][1] = (f16v)(0.f);
  acch[1][0] = (f16v)(0.f); acch[1][1] = (f16v)(0.f);
  sweep32zh(accg, acch, Bz, Bz + 16384, Bh, Bh + 16384, x_l, h_l, l31, hi);

  // ---- z epilogue -> parked in d_out (thread-private packed dwords; v14/v15-proven)
#pragma unroll
  for (int fa = 0; fa < 2; ++fa)
#pragma unroll
    for (int fb = 0; fb < 2; ++fb) {
      const int col = wv * 64 + fb * 32 + l31;
      const float bv = bz[col];
#pragma unroll
      for (int qq = 0; qq < 8; ++qq) {
        const int q0 = 2 * qq;
        const int r0 = fa * 32 + CROW(q0, hi);
        outw[(size_t)(row0 + r0) * 256 + col] =
            pk2(sig_(accg[fa][fb][q0] + bv), sig_(accg[fa][fb][q0 + 1] + bv));
      }
    }

  // ===== PASS r: r = sigmoid(x Wr + h Ur + br); rh = r * h_prev -> parked in h_l
  accg[0][0] = (f16v)(0.f); accg[0][1] = (f16v)(0.f);
  accg[1][0] = (f16v)(0.f); accg[1][1] = (f16v)(0.f);
  sweep32(accg, Br, Br + 16384, x_l, h_l, l31, hi);
  {
    unsigned int rhp[2][2][8];               // transient 32 VGPR (spans one barrier)
#pragma unroll
    for (int fa = 0; fa < 2; ++fa)
#pragma unroll
      for (int fb = 0; fb < 2; ++fb) {
        const int col = wv * 64 + fb * 32 + l31;
        const float bv = br[col];
#pragma unroll
        for (int qq = 0; qq < 8; ++qq) {
          const int q0 = 2 * qq;
          const int r0 = fa * 32 + CROW(q0, hi);
          const float rr0 = sig_(accg[fa][fb][q0]     + bv) * ldsA_get(h_l, r0,     col);
          const float rr1 = sig_(accg[fa][fb][q0 + 1] + bv) * ldsA_get(h_l, r0 + 1, col);
          rhp[fa][fb][qq] = pk2(rr0, rr1);
        }
      }
    __syncthreads();                         // B2: all GEMM + epilogue reads of h_l done
#pragma unroll
    for (int fa = 0; fa < 2; ++fa)
#pragma unroll
      for (int fb = 0; fb < 2; ++fb) {
        const int col = wv * 64 + fb * 32 + l31;
#pragma unroll
        for (int qq = 0; qq < 8; ++qq) {
          const int q0 = 2 * qq;
          const int r0 = fa * 32 + CROW(q0, hi);
          const unsigned int w = rhp[fa][fb][qq];
          ldsA_put(h_l, r0,     col, (unsigned short)(w & 0xffffu));
          ldsA_put(h_l, r0 + 1, col, (unsigned short)(w >> 16));
        }
      }
  }
  __syncthreads();                           // B3: rh visible to all waves

  // ===== PASS h (rh half only): acch += rh * Uh  (kt 16..31 -> +8192 shorts)
  sweep16h(acch, Bh + 8192, Bh + 16384 + 8192, h_l, l31, hi);

  // ===== final epilogue: h = z*h_prev + (1-z)*h_hat (z from d_out, h_prev from global)
#pragma unroll
  for (int fa = 0; fa < 2; ++fa)
#pragma unroll
    for (int fb = 0; fb < 2; ++fb) {
      const int col = wv * 64 + fb * 32 + l31;
      const float bv = bh[col];
#pragma unroll
      for (int qq = 0; qq < 8; ++qq) {
        const int q0 = 2 * qq;
        const int r0 = fa * 32 + CROW(q0, hi);
        const unsigned int zw = outw[(size_t)(row0 + r0) * 256 + col];
#pragma unroll
        for (int j = 0; j < 2; ++j) {
          const int row = r0 + j;
          const size_t oi = (size_t)(row0 + row) * 256 + col;
          const float hh = tanh_(acch[fa][fb][q0 + j] + bv);
          const float z = bf2f((unsigned short)(j ? (zw >> 16) : (zw & 0xffffu)));
          out[oi] = z * hp[oi] + (1.0f - z) * hh;
        }
      }
    }
}

extern "C" void kernel_launch(void* const* d_in, const int* in_sizes, int n_in,
                              void* d_out, int out_size, void* d_ws, size_t ws_size,
                              hipStream_t stream) {
  const float* x  = (const float*)d_in[0];
  const float* hp = (const float*)d_in[1];
  const float* Wz = (const float*)d_in[2];
  const float* Uz = (const float*)d_in[3];
  const float* bz = (const float*)d_in[4];
  const float* Wr = (const float*)d_in[5];
  const float* Ur = (const float*)d_in[6];
  const float* br = (const float*)d_in[7];
  const float* Wh = (const float*)d_in[8];
  const float* Uh = (const float*)d_in[9];
  const float* bh = (const float*)d_in[10];

  if (ws_size < (size_t)(512 * 512 + 256 * 512) * sizeof(unsigned short)) return;  // need 768 KB

  unsigned short* wzr = (unsigned short*)d_ws;
  unsigned short* whh = wzr + 512 * 512;

  gru_prep<<<1536, 256, 0, stream>>>(Wz, Uz, Wr, Ur, Wh, Uh, wzr, whh);
  gru_main<<<1024, 256, 0, stream>>>(x, hp, wzr, whh, bz, br, bh, (float*)d_out);
}

// Round 23
// 91.116 us; speedup vs baseline: 1.2496x; 1.2496x over previous
//
#include <hip/hip_runtime.h>
#include <hip/hip_bf16.h>

// GRU cell v23: v16 EXACTLY (32x32x16 MFMA, wave tile 64x64, 4 waves/256 thr,
// 64-row tiles, 64 KB LDS, 2 blocks/CU, (256,2), z in regs, rh parks in h_l,
// 3 barriers, B ring-6/d-5 + A ring-3/d-2 fenced rings) with ONE change:
// s_setprio(1) around each MFMA cluster (T5). Sweeps are barrier-free ->
// waves run at independent phases -> scheduler arbitration has room to help.

typedef __attribute__((ext_vector_type(8)))  short s8v;            // 8 bf16 = 4 VGPR
typedef __attribute__((ext_vector_type(8)))  unsigned short us8;
typedef __attribute__((ext_vector_type(16))) float f16v;           // 32x32 acc tile
typedef __attribute__((ext_vector_type(4)))  float f4v;

__device__ __forceinline__ float bf2f(unsigned short u) {
  union { unsigned int i; float f; } c; c.i = ((unsigned int)u) << 16; return c.f;
}
__device__ __forceinline__ unsigned short f2bf(float f) {
  __hip_bfloat16 b = __float2bfloat16(f);            // RNE, pairs into v_cvt_pk_bf16_f32
  union { __hip_bfloat16 b; unsigned short u; } c; c.b = b; return c.u;
}
__device__ __forceinline__ unsigned int pk2(float lo, float hi) {
  return (unsigned int)f2bf(lo) | ((unsigned int)f2bf(hi) << 16);
}
__device__ __forceinline__ float sig_(float s)  { return 1.0f / (1.0f + __expf(-s)); }
__device__ __forceinline__ float tanh_(float s) { return 2.0f / (1.0f + __expf(-2.0f * s)) - 1.0f; }

// ---------------- weight prep: fp32 [K][N] -> bf16 32-col fragment tiles ----------------
// Tile (nt, kt) = 32 n x 16 k = 512 shorts (1 KB), lane-major:
//   n = nt*32 + (lane&31), k = kt*16 + (lane>>5)*8 + e ; tile index t = nt*32 + kt.
// wzr: nt 0..7 = Wz/Uz, nt 8..15 = Wr/Ur. whh: nt 0..7 = Wh/Uh. k<256 -> W, else U.
__global__ void gru_prep(const float* __restrict__ Wz, const float* __restrict__ Uz,
                         const float* __restrict__ Wr, const float* __restrict__ Ur,
                         const float* __restrict__ Wh, const float* __restrict__ Uh,
                         unsigned short* __restrict__ wzr, unsigned short* __restrict__ whh) {
  int idx = blockIdx.x * 256 + threadIdx.x;
  if (idx < 512 * 512) {
    int t = idx >> 9, s = idx & 511, lane = s >> 3, e = s & 7;
    int nt = t >> 5, kt = t & 31;
    int n = nt * 32 + (lane & 31);
    int k = kt * 16 + ((lane >> 5) << 3) + e;
    int nn = n & 255;
    float v;
    if (n < 256) v = (k < 256) ? Wz[k * 256 + nn] : Uz[(k - 256) * 256 + nn];
    else         v = (k < 256) ? Wr[k * 256 + nn] : Ur[(k - 256) * 256 + nn];
    wzr[idx] = f2bf(v);
  } else if (idx < 512 * 512 + 256 * 512) {
    int j = idx - 512 * 512;
    int t = j >> 9, s = j & 511, lane = s >> 3, e = s & 7;
    int nt = t >> 5, kt = t & 31;
    int n = nt * 32 + (lane & 31);
    int k = kt * 16 + ((lane >> 5) << 3) + e;
    float v = (k < 256) ? Wh[k * 256 + n] : Uh[(k - 256) * 256 + n];
    whh[j] = f2bf(v);
  }
}

#define MFMA32(a, b, c) __builtin_amdgcn_mfma_f32_32x32x16_bf16((a), (b), (c), 0, 0, 0)

// ---- K=512 sweep: 32 chunks of 16; A = x_l (c<16) then h_l (c>=16) ----
// B: ring-6 distance-5 ; A: ring-3 distance-2. Static indices; fenced.
// s_setprio(1) wraps the MFMA cluster (T5).
__device__ __forceinline__ void sweep32(f16v acc[2][2],
    const unsigned short* __restrict__ b0p, const unsigned short* __restrict__ b1p,
    const unsigned short* Ax, const unsigned short* Ah, int l31, int hi)
{
  const int r7 = l31 & 7;                    // rows l31 and 32+l31 share (row&7)
  const unsigned short* Ax0 = Ax + l31 * 256;
  const unsigned short* Ax1 = Ax + (32 + l31) * 256;
  const unsigned short* Ah0 = Ah + l31 * 256;
  const unsigned short* Ah1 = Ah + (32 + l31) * 256;
  s8v b[6][2];
  s8v a[3][2];
#pragma unroll
  for (int i = 0; i < 5; ++i) {
    b[i][0] = *(const s8v*)(b0p + i * 512);
    b[i][1] = *(const s8v*)(b1p + i * 512);
  }
  a[0][0] = *(const s8v*)(Ax0 + ((0 + hi) ^ r7) * 8);
  a[0][1] = *(const s8v*)(Ax1 + ((0 + hi) ^ r7) * 8);
  a[1][0] = *(const s8v*)(Ax0 + ((2 + hi) ^ r7) * 8);
  a[1][1] = *(const s8v*)(Ax1 + ((2 + hi) ^ r7) * 8);
#pragma unroll
  for (int c = 0; c < 32; ++c) {
    if (c + 5 < 32) {
      const int s = (c + 5) % 6;
      b[s][0] = *(const s8v*)(b0p + (c + 5) * 512);
      b[s][1] = *(const s8v*)(b1p + (c + 5) * 512);
    }
    if (c + 2 < 32) {
      const int cn = c + 2;
      const int kk = cn & 15;
      const int gp = ((kk * 2 + hi) ^ r7) * 8;
      const int s = cn % 3;
      if (cn < 16) { a[s][0] = *(const s8v*)(Ax0 + gp); a[s][1] = *(const s8v*)(Ax1 + gp); }
      else         { a[s][0] = *(const s8v*)(Ah0 + gp); a[s][1] = *(const s8v*)(Ah1 + gp); }
    }
    __builtin_amdgcn_sched_barrier(0);
    const int sb = c % 6, sa = c % 3;
    __builtin_amdgcn_s_setprio(1);
    acc[0][0] = MFMA32(a[sa][0], b[sb][0], acc[0][0]);
    acc[0][1] = MFMA32(a[sa][0], b[sb][1], acc[0][1]);
    acc[1][0] = MFMA32(a[sa][1], b[sb][0], acc[1][0]);
    acc[1][1] = MFMA32(a[sa][1], b[sb][1], acc[1][1]);
    __builtin_amdgcn_s_setprio(0);
    __builtin_amdgcn_sched_barrier(0);
  }
}

// swizzled scalar LDS accessors (granule-XOR layout)
__device__ __forceinline__ float ldsA_get(const unsigned short* A, int row, int col) {
  int gp = ((col >> 3) ^ (row & 7));
  return bf2f(A[row * 256 + gp * 8 + (col & 7)]);
}
__device__ __forceinline__ void ldsA_put(unsigned short* A, int row, int col, unsigned short v) {
  int gp = ((col >> 3) ^ (row & 7));
  A[row * 256 + gp * 8 + (col & 7)] = v;
}

// C-tile row for reg q (m74/m101 verified): (q&3) + 8*(q>>2) + 4*hi
#define CROW(q, hi) (((q) & 3) + 8 * ((q) >> 2) + 4 * (hi))

// ---------------- main fused kernel: 64 rows per block, 4 waves ----------------
__global__ __launch_bounds__(256, 2) void gru_main(
    const float* __restrict__ x, const float* __restrict__ hp,
    const unsigned short* __restrict__ wzr, const unsigned short* __restrict__ whh,
    const float* __restrict__ bz, const float* __restrict__ br, const float* __restrict__ bh,
    float* __restrict__ out)
{
  __shared__ __align__(16) unsigned short x_l[64 * 256];   // 32 KB; x (bf16, XOR layout)
  __shared__ __align__(16) unsigned short h_l[64 * 256];   // 32 KB; h_prev, later rh

  const int tid = threadIdx.x;
  const int lane = tid & 63;
  const int wv = tid >> 6;                   // 0..3 : wave's 64-col slice
  const int l31 = lane & 31, hi = lane >> 5;
  const int row0 = blockIdx.x * 64;

  // B tile streams (nt stride 16384 shorts = 32 chunks x 512); wave owns nt wv*2, wv*2+1
  const unsigned short* Bz = wzr + (size_t)(wv * 2) * 16384 + lane * 8;
  const unsigned short* Br = wzr + 131072 + (size_t)(wv * 2) * 16384 + lane * 8;
  const unsigned short* Bh = whh + (size_t)(wv * 2) * 16384 + lane * 8;

  // ---- stage x, h tiles to LDS (fp32 -> bf16), granule-XOR layout; 64 elems/thread/array
  {
    const int srow = tid >> 2;               // 0..63
    const int part = tid & 3;                // 64 cols = 8 granules each
    const float* xs = x  + (size_t)(row0 + srow) * 256 + part * 64;
    const float* hs = hp + (size_t)(row0 + srow) * 256 + part * 64;
    unsigned short* xd = x_l + srow * 256;
    unsigned short* hd = h_l + srow * 256;
    const int r7 = srow & 7;
#pragma unroll
    for (int j = 0; j < 8; ++j) {
      int gp = (part * 8 + j) ^ r7;
      f4v v0 = *(const f4v*)(xs + j * 8);
      f4v v1 = *(const f4v*)(xs + j * 8 + 4);
      us8 o;
      o[0]=f2bf(v0[0]); o[1]=f2bf(v0[1]); o[2]=f2bf(v0[2]); o[3]=f2bf(v0[3]);
      o[4]=f2bf(v1[0]); o[5]=f2bf(v1[1]); o[6]=f2bf(v1[2]); o[7]=f2bf(v1[3]);
      *(us8*)(xd + gp * 8) = o;
    }
#pragma unroll
    for (int j = 0; j < 8; ++j) {
      int gp = (part * 8 + j) ^ r7;
      f4v v0 = *(const f4v*)(hs + j * 8);
      f4v v1 = *(const f4v*)(hs + j * 8 + 4);
      us8 o;
      o[0]=f2bf(v0[0]); o[1]=f2bf(v0[1]); o[2]=f2bf(v0[2]); o[3]=f2bf(v0[3]);
      o[4]=f2bf(v1[0]); o[5]=f2bf(v1[1]); o[6]=f2bf(v1[2]); o[7]=f2bf(v1[3]);
      *(us8*)(hd + gp * 8) = o;
    }
  }
  __syncthreads();                           // B1

  f16v acc[2][2];
  unsigned int zp[2][2][8];                  // z gate, packed bf16 : 32 VGPR

  // ===== PASS z: z = sigmoid(x Wz + h Uz + bz) -> zp (registers)
  acc[0][0] = (f16v)(0.f); acc[0][1] = (f16v)(0.f);
  acc[1][0] = (f16v)(0.f); acc[1][1] = (f16v)(0.f);
  sweep32(acc, Bz, Bz + 16384, x_l, h_l, l31, hi);
#pragma unroll
  for (int fa = 0; fa < 2; ++fa)
#pragma unroll
    for (int fb = 0; fb < 2; ++fb) {
      const int col = wv * 64 + fb * 32 + l31;
      const float bv = bz[col];
#pragma unroll
      for (int qq = 0; qq < 8; ++qq) {
        const int q0 = 2 * qq;
        zp[fa][fb][qq] = pk2(sig_(acc[fa][fb][q0] + bv), sig_(acc[fa][fb][q0 + 1] + bv));
      }
    }

  // ===== PASS r: r = sigmoid(x Wr + h Ur + br); rh = r * h_prev -> parked in h_l
  acc[0][0] = (f16v)(0.f); acc[0][1] = (f16v)(0.f);
  acc[1][0] = (f16v)(0.f); acc[1][1] = (f16v)(0.f);
  sweep32(acc, Br, Br + 16384, x_l, h_l, l31, hi);
  {
    unsigned int rhp[2][2][8];               // transient 32 VGPR (spans one barrier)
#pragma unroll
    for (int fa = 0; fa < 2; ++fa)
#pragma unroll
      for (int fb = 0; fb < 2; ++fb) {
        const int col = wv * 64 + fb * 32 + l31;
        const float bv = br[col];
#pragma unroll
        for (int qq = 0; qq < 8; ++qq) {
          const int q0 = 2 * qq;
          const int r0 = fa * 32 + CROW(q0, hi);
          const float rr0 = sig_(acc[fa][fb][q0]     + bv) * ldsA_get(h_l, r0,     col);
          const float rr1 = sig_(acc[fa][fb][q0 + 1] + bv) * ldsA_get(h_l, r0 + 1, col);
          rhp[fa][fb][qq] = pk2(rr0, rr1);
        }
      }
    __syncthreads();                         // B2: all z/r GEMM + epilogue reads of h_l done
#pragma unroll
    for (int fa = 0; fa < 2; ++fa)
#pragma unroll
      for (int fb = 0; fb < 2; ++fb) {
        const int col = wv * 64 + fb * 32 + l31;
#pragma unroll
        for (int qq = 0; qq < 8; ++qq) {
          const int q0 = 2 * qq;
          const int r0 = fa * 32 + CROW(q0, hi);
          const unsigned int w = rhp[fa][fb][qq];
          ldsA_put(h_l, r0,     col, (unsigned short)(w & 0xffffu));
          ldsA_put(h_l, r0 + 1, col, (unsigned short)(w >> 16));
        }
      }
  }
  __syncthreads();                           // B3: rh visible to all waves

  // ===== PASS h: h_hat = tanh(x Wh + rh Uh + bh); h_l now holds rh
  acc[0][0] = (f16v)(0.f); acc[0][1] = (f16v)(0.f);
  acc[1][0] = (f16v)(0.f); acc[1][1] = (f16v)(0.f);
  sweep32(acc, Bh, Bh + 16384, x_l, h_l, l31, hi);

  // ===== final epilogue: h = z*h_prev + (1-z)*h_hat (z from regs, h_prev from global)
#pragma unroll
  for (int fa = 0; fa < 2; ++fa)
#pragma unroll
    for (int fb = 0; fb < 2; ++fb) {
      const int col = wv * 64 + fb * 32 + l31;
      const float bv = bh[col];
#pragma unroll
      for (int qq = 0; qq < 8; ++qq) {
        const int q0 = 2 * qq;
        const int r0 = fa * 32 + CROW(q0, hi);
        const unsigned int zw = zp[fa][fb][qq];
#pragma unroll
        for (int j = 0; j < 2; ++j) {
          const int row = r0 + j;
          const size_t oi = (size_t)(row0 + row) * 256 + col;
          const float hh = tanh_(acc[fa][fb][q0 + j] + bv);
          const float z = bf2f((unsigned short)(j ? (zw >> 16) : (zw & 0xffffu)));
          out[oi] = z * hp[oi] + (1.0f - z) * hh;
        }
      }
    }
}

extern "C" void kernel_launch(void* const* d_in, const int* in_sizes, int n_in,
                              void* d_out, int out_size, void* d_ws, size_t ws_size,
                              hipStream_t stream) {
  const float* x  = (const float*)d_in[0];
  const float* hp = (const float*)d_in[1];
  const float* Wz = (const float*)d_in[2];
  const float* Uz = (const float*)d_in[3];
  const float* bz = (const float*)d_in[4];
  const float* Wr = (const float*)d_in[5];
  const float* Ur = (const float*)d_in[6];
  const float* br = (const float*)d_in[7];
  const float* Wh = (const float*)d_in[8];
  const float* Uh = (const float*)d_in[9];
  const float* bh = (const float*)d_in[10];

  if (ws_size < (size_t)(512 * 512 + 256 * 512) * sizeof(unsigned short)) return;  // need 768 KB

  unsigned short* wzr = (unsigned short*)d_ws;
  unsigned short* whh = wzr + 512 * 512;

  gru_prep<<<1536, 256, 0, stream>>>(Wz, Uz, Wr, Ur, Wh, Uh, wzr, whh);
  gru_main<<<1024, 256, 0, stream>>>(x, hp, wzr, whh, bz, br, bh, (float*)d_out);
}